// Round 20
// baseline (185.850 us; speedup 1.0000x reference)
//
#include <hip/hip_runtime.h>

#define B_ 4
#define N0_ 50000
#define N1_ 25000
#define N2_ 12500
#define E0_ 800000
#define E1_ 400000
#define CIN_ 32
#define CS_ 16
#define COUT_ 32
#define EPS_ 1e-5f
#define CAP_ 80               // single bucket/node (max in-degree <= 80 proven r10/r13)
#define SST1_ 3200
#define SST2_ 1600

__device__ __forceinline__ int slice_of(int d) { return (d >> 2) & 7; }
__device__ __forceinline__ int curix(int d, int sst) {
    return ((d >> 2) & 7) * sst + ((d >> 5) << 2) + (d & 3);
}
__device__ __forceinline__ float sigmoidf_(float x) {
    return __builtin_amdgcn_rcpf(1.0f + __expf(-x));
}

// ---- pack edges into pairs {src<<16|dst}x2 + {bf16 w}x2 + zero cursors + prep ----
__global__ void pack_prep(const int* __restrict__ ei0, const float* __restrict__ ew0,
                          const int* __restrict__ ei1, const float* __restrict__ ew1,
                          uint2* __restrict__ pk0, unsigned* __restrict__ wq0,
                          uint2* __restrict__ pk1, unsigned* __restrict__ wq1,
                          int* __restrict__ curz, int ztot,
                          const float* __restrict__ Q1, const float* __restrict__ K1,
                          const float* __restrict__ Watt1,
                          const float* __restrict__ Q2, const float* __restrict__ K2,
                          const float* __restrict__ Watt2,
                          const float* __restrict__ We1, const float* __restrict__ We2,
                          float* __restrict__ qv1, float* __restrict__ kv1,
                          float* __restrict__ qv2, float* __restrict__ kv2,
                          float* __restrict__ se) {
    int gid = blockIdx.x * blockDim.x + threadIdx.x;
    int stride = gridDim.x * blockDim.x;
    for (int i = gid; i < ztot; i += stride) curz[i] = 0;
    for (int pe = gid; pe < E0_ / 2; pe += stride) {
        int e = 2 * pe;
        uint2 p;
        p.x = (unsigned)ei0[e] << 16 | (unsigned)ei0[E0_ + e];
        p.y = (unsigned)ei0[e + 1] << 16 | (unsigned)ei0[E0_ + e + 1];
        pk0[pe] = p;
        unsigned w0 = (__float_as_uint(ew0[e]) + 0x8000u) >> 16;
        unsigned w1 = (__float_as_uint(ew0[e + 1]) + 0x8000u) >> 16;
        wq0[pe] = w0 | (w1 << 16);
    }
    for (int pe = gid; pe < E1_ / 2; pe += stride) {
        int e = 2 * pe;
        uint2 p;
        p.x = (unsigned)ei1[e] << 16 | (unsigned)ei1[E1_ + e];
        p.y = (unsigned)ei1[e + 1] << 16 | (unsigned)ei1[E1_ + e + 1];
        pk1[pe] = p;
        unsigned w0 = (__float_as_uint(ew1[e]) + 0x8000u) >> 16;
        unsigned w1 = (__float_as_uint(ew1[e + 1]) + 0x8000u) >> 16;
        wq1[pe] = w0 | (w1 << 16);
    }
    if (blockIdx.x == 0) {
        int t = threadIdx.x;
        if (t < CS_) {
            float q = 0.f, k = 0.f;
            for (int c = 0; c < CS_; ++c) {
                q += Q1[t * CS_ + c] * Watt1[c];
                k += K1[t * CS_ + c] * Watt1[CS_ + c];
            }
            qv1[t] = q; kv1[t] = k;
        }
        if (t < COUT_) {
            float q = 0.f, k = 0.f;
            for (int c = 0; c < COUT_; ++c) {
                q += Q2[t * COUT_ + c] * Watt2[c];
                k += K2[t * COUT_ + c] * Watt2[COUT_ + c];
            }
            qv2[t] = q; kv2[t] = k;
        }
        if (t == 64) {
            float s1 = 0.f, s2 = 0.f;
            for (int c = 0; c < CS_; ++c) s1 += We1[c] * Watt1[2 * CS_ + c];
            for (int c = 0; c < COUT_; ++c) s2 += We2[c] * Watt2[2 * COUT_ + c];
            se[0] = s1; se[1] = s2;
        }
    }
}

// ---- layer1 node transform: bf16 xs rows + fp32 xd + per-node att scalars ----
__global__ void node_xform1(const float* __restrict__ X, const int* __restrict__ res,
                            const float* __restrict__ Wn,
                            const float* __restrict__ qv, const float* __restrict__ kv,
                            unsigned short* __restrict__ xsb, float* __restrict__ xd_t,
                            float* __restrict__ aj, float* __restrict__ ai) {
    int lane = threadIdx.x & 63;
    int n = blockIdx.x * (blockDim.x >> 6) + (threadIdx.x >> 6);
    if (n >= N1_) return;
    int b = lane >> 4;
    int c = lane & 15;
    int rn = res[n];
    const float4* Xs4 = (const float4*)(X + ((size_t)b * N0_ + n) * CIN_);
    const float4* Xd4 = (const float4*)(X + ((size_t)b * N0_ + rn) * CIN_);
    float s = 0.f, d = 0.f;
#pragma unroll
    for (int k4 = 0; k4 < CIN_ / 4; ++k4) {
        float4 xs4 = Xs4[k4];
        float4 xd4 = Xd4[k4];
        int k = 4 * k4;
        float w0 = Wn[(k + 0) * CS_ + c], w1 = Wn[(k + 1) * CS_ + c];
        float w2 = Wn[(k + 2) * CS_ + c], w3 = Wn[(k + 3) * CS_ + c];
        s += xs4.x * w0 + xs4.y * w1 + xs4.z * w2 + xs4.w * w3;
        d += xd4.x * w0 + xd4.y * w1 + xd4.z * w2 + xd4.w * w3;
    }
    xsb[(size_t)n * 64 + lane] = (unsigned short)((__float_as_uint(s) + 0x8000u) >> 16);
    xd_t[(size_t)n * 64 + lane] = d;
    float p = s * qv[c];
    float q = d * kv[c];
#pragma unroll
    for (int m = 1; m < 16; m <<= 1) {
        p += __shfl_xor(p, m, 16);
        q += __shfl_xor(q, m, 16);
    }
    if (c == 0) {
        aj[n * 4 + b] = p;
        ai[n * 4 + b] = q;
    }
}

// ---- XCD-sliced scatter with fused attention: pair-coalesced stream ----
template <int SST>
__global__ void scatter_att(const uint2* __restrict__ pk2, const unsigned* __restrict__ wq2,
                            int Epairs, const float* __restrict__ aj, const float* __restrict__ ai,
                            const float* __restrict__ sep, const float* __restrict__ batt,
                            int* __restrict__ cur, uint2* __restrict__ buf) {
    int slice = blockIdx.x & 7;
    int chunk = blockIdx.x >> 3;
    int nch = gridDim.x >> 3;
    float se = sep[0], b0 = batt[0];
    for (int pe = chunk * 256 + threadIdx.x; pe < Epairs; pe += nch * 256) {
        uint2 pv = pk2[pe];
        unsigned wpair = wq2[pe];
        // edge A
        int da = pv.x & 0xffff;
        if (slice_of(da) == slice) {
            int s = pv.x >> 16;
            unsigned wu = wpair & 0xffffu;
            float w = __uint_as_float(wu << 16);
            float4 A = ((const float4*)aj)[s];
            float4 I = ((const float4*)ai)[da];
            float base = fmaf(w, se, b0);
            unsigned q =  __float2uint_rn(sigmoidf_(A.x + I.x + base) * 255.f)
                       | (__float2uint_rn(sigmoidf_(A.y + I.y + base) * 255.f) << 8)
                       | (__float2uint_rn(sigmoidf_(A.z + I.z + base) * 255.f) << 16)
                       | (__float2uint_rn(sigmoidf_(A.w + I.w + base) * 255.f) << 24);
            int p = atomicAdd(&cur[curix(da, SST)], 1);
            if (p < CAP_)
                buf[(size_t)da * CAP_ + p] = make_uint2((wu << 16) | (unsigned)s, q);
        }
        // edge B
        int db = pv.y & 0xffff;
        if (slice_of(db) == slice) {
            int s = pv.y >> 16;
            unsigned wu = wpair >> 16;
            float w = __uint_as_float(wu << 16);
            float4 A = ((const float4*)aj)[s];
            float4 I = ((const float4*)ai)[db];
            float base = fmaf(w, se, b0);
            unsigned q =  __float2uint_rn(sigmoidf_(A.x + I.x + base) * 255.f)
                       | (__float2uint_rn(sigmoidf_(A.y + I.y + base) * 255.f) << 8)
                       | (__float2uint_rn(sigmoidf_(A.z + I.z + base) * 255.f) << 16)
                       | (__float2uint_rn(sigmoidf_(A.w + I.w + base) * 255.f) << 24);
            int p = atomicAdd(&cur[curix(db, SST)], 1);
            if (p < CAP_)
                buf[(size_t)db * CAP_ + p] = make_uint2((wu << 16) | (unsigned)s, q);
        }
    }
}

// ---- layer1 fused edge+epilogue (unroll-8) ----
__global__ void edge_fused1(const int* __restrict__ cur, const uint2* __restrict__ buf,
                            const unsigned short* __restrict__ xsb,
                            const float* __restrict__ xd_t, const float* __restrict__ We,
                            const float* __restrict__ Wc, const float* __restrict__ bc,
                            float* __restrict__ h_t) {
    int lane = threadIdx.x & 63;
    int n = blockIdx.x * (blockDim.x >> 6) + (threadIdx.x >> 6);
    if (n >= N1_) return;
    int b = lane >> 4;
    int c = lane & 15;
    int sh = 8 * b;
    float wec = We[c];
    float acc = 0.f;
    int cnt = cur[curix(n, SST1_)];
    if (cnt > CAP_) cnt = CAP_;
    const uint2* bp = buf + (size_t)n * CAP_;
    int i = 0;
    for (; i + 8 <= cnt; i += 8) {
        uint2 v[8];
#pragma unroll
        for (int j = 0; j < 8; ++j) v[j] = bp[i + j];
        float xj[8], a[8], g[8];
#pragma unroll
        for (int j = 0; j < 8; ++j) {
            int sj = v[j].x & 0xffff;
            xj[j] = __uint_as_float((unsigned)xsb[(size_t)sj * 64 + lane] << 16);
            a[j] = (float)((v[j].y >> sh) & 0xff) * (1.f / 255.f);
            g[j] = sigmoidf_(__uint_as_float(v[j].x & 0xffff0000u) * wec);
        }
#pragma unroll
        for (int j = 0; j < 8; ++j) acc += a[j] * g[j] * xj[j];
    }
    for (; i < cnt; ++i) {
        uint2 v0 = bp[i];
        int s0 = v0.x & 0xffff;
        float w0 = __uint_as_float(v0.x & 0xffff0000u);
        float xj0 = __uint_as_float((unsigned)xsb[(size_t)s0 * 64 + lane] << 16);
        float a0 = (float)((v0.y >> sh) & 0xff) * (1.f / 255.f);
        acc += a0 * sigmoidf_(w0 * wec) * xj0;
    }
    // fused epilogue
    float xv = xd_t[(size_t)n * 64 + lane];
    float o = bc[c];
#pragma unroll
    for (int k = 0; k < CS_; ++k) {
        o += __shfl(xv, k, 16) * Wc[k * CS_ + c];
        o += __shfl(acc, k, 16) * Wc[(CS_ + k) * CS_ + c];
    }
    float s = o, sq = o * o;
#pragma unroll
    for (int m = 1; m < 64; m <<= 1) {
        s += __shfl_xor(s, m);
        sq += __shfl_xor(sq, m);
    }
    float mean = s * (1.f / 64.f);
    float var = (sq - 64.f * mean * mean) * (1.f / 63.f);
    float inv = __builtin_amdgcn_rsqf(var + EPS_);
    float v = xv + (o - mean) * inv;
    h_t[(size_t)n * 64 + lane] = v > 0.f ? v : 0.01f * v;
}

// ---- layer2 node transform ----
__global__ void node_xform2(const float* __restrict__ h_t, const int* __restrict__ res,
                            const float* __restrict__ Wn,
                            const float* __restrict__ qv, const float* __restrict__ kv,
                            unsigned short* __restrict__ xsb, float* __restrict__ xd_t,
                            float* __restrict__ aj, float* __restrict__ ai) {
    int lane = threadIdx.x & 63;
    int n = blockIdx.x * (blockDim.x >> 6) + (threadIdx.x >> 6);
    if (n >= N2_) return;
    int bl = lane >> 5;
    int c = lane & 31;
    int rn = res[n];
    float qc = qv[c], kc = kv[c];
#pragma unroll
    for (int j = 0; j < 2; ++j) {
        int b = bl + 2 * j;
        const float* hs = h_t + (size_t)n * 64 + b * 16;
        const float* hd = h_t + (size_t)rn * 64 + b * 16;
        float s = 0.f, d = 0.f;
#pragma unroll
        for (int k = 0; k < CS_; ++k) {
            float w = Wn[k * COUT_ + c];
            s += hs[k] * w;
            d += hd[k] * w;
        }
        xsb[(size_t)n * 128 + b * 32 + c] = (unsigned short)((__float_as_uint(s) + 0x8000u) >> 16);
        xd_t[(size_t)n * 128 + b * 32 + c] = d;
        float p = s * qc;
        float q = d * kc;
#pragma unroll
        for (int m = 1; m < 32; m <<= 1) {
            p += __shfl_xor(p, m, 32);
            q += __shfl_xor(q, m, 32);
        }
        if (c == 0) {
            aj[n * 4 + b] = p;
            ai[n * 4 + b] = q;
        }
    }
}

// ---- layer2 fused edge+epilogue -> d_out (unroll-4) ----
__global__ void edge_fused2(const int* __restrict__ cur, const uint2* __restrict__ buf,
                            const unsigned short* __restrict__ xsb,
                            const float* __restrict__ xd_t, const float* __restrict__ We,
                            const float* __restrict__ Wc, const float* __restrict__ bc,
                            float* __restrict__ out) {
    int lane = threadIdx.x & 63;
    int n = blockIdx.x * (blockDim.x >> 6) + (threadIdx.x >> 6);
    if (n >= N2_) return;
    int bl = lane >> 5;
    int c = lane & 31;
    int sh0 = 8 * bl;
    float wec = We[c];
    float acc0 = 0.f, acc1 = 0.f;
    int cnt = cur[curix(n, SST2_)];
    if (cnt > CAP_) cnt = CAP_;
    const uint2* bp = buf + (size_t)n * CAP_;
    int i = 0;
    for (; i + 4 <= cnt; i += 4) {
        uint2 v0 = bp[i], v1 = bp[i + 1], v2 = bp[i + 2], v3 = bp[i + 3];
        int s0 = v0.x & 0xffff, s1 = v1.x & 0xffff;
        int s2 = v2.x & 0xffff, s3 = v3.x & 0xffff;
        float w0 = __uint_as_float(v0.x & 0xffff0000u);
        float w1 = __uint_as_float(v1.x & 0xffff0000u);
        float w2 = __uint_as_float(v2.x & 0xffff0000u);
        float w3 = __uint_as_float(v3.x & 0xffff0000u);
        float xj00 = __uint_as_float((unsigned)xsb[(size_t)s0 * 128 + lane] << 16);
        float xj01 = __uint_as_float((unsigned)xsb[(size_t)s0 * 128 + 64 + lane] << 16);
        float xj10 = __uint_as_float((unsigned)xsb[(size_t)s1 * 128 + lane] << 16);
        float xj11 = __uint_as_float((unsigned)xsb[(size_t)s1 * 128 + 64 + lane] << 16);
        float xj20 = __uint_as_float((unsigned)xsb[(size_t)s2 * 128 + lane] << 16);
        float xj21 = __uint_as_float((unsigned)xsb[(size_t)s2 * 128 + 64 + lane] << 16);
        float xj30 = __uint_as_float((unsigned)xsb[(size_t)s3 * 128 + lane] << 16);
        float xj31 = __uint_as_float((unsigned)xsb[(size_t)s3 * 128 + 64 + lane] << 16);
        float g0 = sigmoidf_(w0 * wec);
        float g1 = sigmoidf_(w1 * wec);
        float g2 = sigmoidf_(w2 * wec);
        float g3 = sigmoidf_(w3 * wec);
        acc0 += (float)((v0.y >> sh0) & 0xff) * (1.f / 255.f) * g0 * xj00;
        acc1 += (float)((v0.y >> (sh0 + 16)) & 0xff) * (1.f / 255.f) * g0 * xj01;
        acc0 += (float)((v1.y >> sh0) & 0xff) * (1.f / 255.f) * g1 * xj10;
        acc1 += (float)((v1.y >> (sh0 + 16)) & 0xff) * (1.f / 255.f) * g1 * xj11;
        acc0 += (float)((v2.y >> sh0) & 0xff) * (1.f / 255.f) * g2 * xj20;
        acc1 += (float)((v2.y >> (sh0 + 16)) & 0xff) * (1.f / 255.f) * g2 * xj21;
        acc0 += (float)((v3.y >> sh0) & 0xff) * (1.f / 255.f) * g3 * xj30;
        acc1 += (float)((v3.y >> (sh0 + 16)) & 0xff) * (1.f / 255.f) * g3 * xj31;
    }
    for (; i < cnt; ++i) {
        uint2 v0 = bp[i];
        int s0 = v0.x & 0xffff;
        float w0 = __uint_as_float(v0.x & 0xffff0000u);
        float xj00 = __uint_as_float((unsigned)xsb[(size_t)s0 * 128 + lane] << 16);
        float xj01 = __uint_as_float((unsigned)xsb[(size_t)s0 * 128 + 64 + lane] << 16);
        float a00 = (float)((v0.y >> sh0) & 0xff) * (1.f / 255.f);
        float a01 = (float)((v0.y >> (sh0 + 16)) & 0xff) * (1.f / 255.f);
        float g0 = sigmoidf_(w0 * wec);
        acc0 += a00 * g0 * xj00;
        acc1 += a01 * g0 * xj01;
    }
    // fused epilogue
    float xv0 = xd_t[(size_t)n * 128 + lane];
    float xv1 = xd_t[(size_t)n * 128 + 64 + lane];
    float o0 = bc[c], o1 = o0;
#pragma unroll
    for (int k = 0; k < COUT_; ++k) {
        float w1 = Wc[k * COUT_ + c];
        float w2 = Wc[(COUT_ + k) * COUT_ + c];
        o0 += __shfl(xv0, k, 32) * w1 + __shfl(acc0, k, 32) * w2;
        o1 += __shfl(xv1, k, 32) * w1 + __shfl(acc1, k, 32) * w2;
    }
    float s = o0 + o1, sq = o0 * o0 + o1 * o1;
#pragma unroll
    for (int m = 1; m < 64; m <<= 1) {
        s += __shfl_xor(s, m);
        sq += __shfl_xor(sq, m);
    }
    float mean = s * (1.f / 128.f);
    float var = (sq - 128.f * mean * mean) * (1.f / 127.f);
    float inv = __builtin_amdgcn_rsqf(var + EPS_);
    float v0 = xv0 + (o0 - mean) * inv;
    float v1 = xv1 + (o1 - mean) * inv;
    out[((size_t)bl * N2_ + n) * COUT_ + c] = v0 > 0.f ? v0 : 0.01f * v0;
    out[((size_t)(bl + 2) * N2_ + n) * COUT_ + c] = v1 > 0.f ? v1 : 0.01f * v1;
}

extern "C" void kernel_launch(void* const* d_in, const int* in_sizes, int n_in,
                              void* d_out, int out_size, void* d_ws, size_t ws_size,
                              hipStream_t stream) {
    (void)in_sizes; (void)n_in; (void)out_size; (void)ws_size;
    const float* X     = (const float*)d_in[0];
    const int*   ei0   = (const int*)d_in[1];
    const float* ew0   = (const float*)d_in[2];
    const int*   rn0   = (const int*)d_in[3];
    const int*   ei1   = (const int*)d_in[4];
    const float* ew1   = (const float*)d_in[5];
    const int*   rn1   = (const int*)d_in[6];
    const float* Wn1   = (const float*)d_in[7];
    const float* We1   = (const float*)d_in[8];
    const float* Q1    = (const float*)d_in[9];
    const float* K1    = (const float*)d_in[10];
    const float* Watt1 = (const float*)d_in[11];
    const float* batt1 = (const float*)d_in[12];
    const float* Wc1   = (const float*)d_in[13];
    const float* bc1   = (const float*)d_in[14];
    const float* Wn2   = (const float*)d_in[15];
    const float* We2   = (const float*)d_in[16];
    const float* Q2    = (const float*)d_in[17];
    const float* K2    = (const float*)d_in[18];
    const float* Watt2 = (const float*)d_in[19];
    const float* batt2 = (const float*)d_in[20];
    const float* Wc2   = (const float*)d_in[21];
    const float* bc2   = (const float*)d_in[22];

    // ---- workspace layout ----
    const size_t BUF = (size_t)B_ * N1_ * CS_;  // 1.6M elements
    float* ws  = (float*)d_ws;
    float* S0  = ws;             // xd1 -> h
    float* S1  = S0 + BUF;       // xd2
    unsigned short* S2 = (unsigned short*)(S1 + BUF);  // xsb (bf16), L1 then L2
    float* aj1 = (float*)(S2 + BUF);
    float* ai1 = aj1 + (size_t)N1_ * 4;
    float* aj2 = ai1 + (size_t)N1_ * 4;
    float* ai2 = aj2 + (size_t)N2_ * 4;
    uint2* ebuf = (uint2*)(ai2 + (size_t)N2_ * 4);   // N1*CAP_ uint2 = 16 MB (L2 reuses)
    int* cur1 = (int*)(ebuf + (size_t)N1_ * CAP_);   // 8*SST1_
    int* cur2 = cur1 + 8 * SST1_;                    // 8*SST2_
    uint2* pk0 = (uint2*)(cur2 + 8 * SST2_);         // E0/2 uint2
    uint2* pk1 = pk0 + E0_ / 2;                      // E1/2 uint2
    unsigned* wq0 = (unsigned*)(pk1 + E1_ / 2);      // E0/2 u32
    unsigned* wq1 = wq0 + E0_ / 2;                   // E1/2 u32
    float* qv1 = (float*)(wq1 + E1_ / 2);
    float* kv1 = qv1 + 16;
    float* qv2 = kv1 + 16;
    float* kv2 = qv2 + 32;
    float* se  = kv2 + 32;

    const int ztot = 8 * SST1_ + 8 * SST2_;
    pack_prep<<<1024, 256, 0, stream>>>(ei0, ew0, ei1, ew1, pk0, wq0, pk1, wq1,
                                        cur1, ztot,
                                        Q1, K1, Watt1, Q2, K2, Watt2, We1, We2,
                                        qv1, kv1, qv2, kv2, se);

    // ---- layer 1 ----
    node_xform1<<<(N1_ + 3) / 4, 256, 0, stream>>>(X, rn0, Wn1, qv1, kv1, S2, S0, aj1, ai1);
    scatter_att<SST1_><<<4096, 256, 0, stream>>>(pk0, wq0, E0_ / 2, aj1, ai1, se, batt1,
                                                 cur1, ebuf);
    edge_fused1<<<(N1_ + 3) / 4, 256, 0, stream>>>(cur1, ebuf, S2, S0, We1, Wc1, bc1, S0);

    // ---- layer 2 (ebuf reused) ----
    node_xform2<<<(N2_ + 3) / 4, 256, 0, stream>>>(S0, rn1, Wn2, qv2, kv2, S2, S1, aj2, ai2);
    scatter_att<SST2_><<<2048, 256, 0, stream>>>(pk1, wq1, E1_ / 2, aj2, ai2, se + 1, batt2,
                                                 cur2, ebuf);
    edge_fused2<<<(N2_ + 3) / 4, 256, 0, stream>>>(cur2, ebuf, S2, S1, We2, Wc2, bc2,
                                                   (float*)d_out);
}

// Round 21
// 172.267 us; speedup vs baseline: 1.0788x; 1.0788x over previous
//
#include <hip/hip_runtime.h>

#define B_ 4
#define N0_ 50000
#define N1_ 25000
#define N2_ 12500
#define E0_ 800000
#define E1_ 400000
#define CIN_ 32
#define CS_ 16
#define COUT_ 32
#define EPS_ 1e-5f
#define CAP_ 80               // single bucket/node (max in-degree <= 80 proven r10/r13)
#define SST1_ 3200
#define SST2_ 1600

__device__ __forceinline__ int slice_of(int d) { return (d >> 2) & 7; }
__device__ __forceinline__ int curix(int d, int sst) {
    return ((d >> 2) & 7) * sst + ((d >> 5) << 2) + (d & 3);
}
__device__ __forceinline__ float sigmoidf_(float x) {
    return __builtin_amdgcn_rcpf(1.0f + __expf(-x));
}

// ---- pack edges {src<<16|dst, bf16 w} + zero cursors + prep derived weights ----
__global__ void pack_prep(const int* __restrict__ ei0, const float* __restrict__ ew0,
                          const int* __restrict__ ei1, const float* __restrict__ ew1,
                          unsigned* __restrict__ pk0, unsigned short* __restrict__ wq0,
                          unsigned* __restrict__ pk1, unsigned short* __restrict__ wq1,
                          int* __restrict__ curz, int ztot,
                          const float* __restrict__ Q1, const float* __restrict__ K1,
                          const float* __restrict__ Watt1,
                          const float* __restrict__ Q2, const float* __restrict__ K2,
                          const float* __restrict__ Watt2,
                          const float* __restrict__ We1, const float* __restrict__ We2,
                          float* __restrict__ qv1, float* __restrict__ kv1,
                          float* __restrict__ qv2, float* __restrict__ kv2,
                          float* __restrict__ se) {
    int gid = blockIdx.x * blockDim.x + threadIdx.x;
    int stride = gridDim.x * blockDim.x;
    for (int i = gid; i < ztot; i += stride) curz[i] = 0;
    for (int e = gid; e < E0_; e += stride) {
        pk0[e] = (unsigned)ei0[e] << 16 | (unsigned)ei0[E0_ + e];
        wq0[e] = (unsigned short)((__float_as_uint(ew0[e]) + 0x8000u) >> 16);
    }
    for (int e = gid; e < E1_; e += stride) {
        pk1[e] = (unsigned)ei1[e] << 16 | (unsigned)ei1[E1_ + e];
        wq1[e] = (unsigned short)((__float_as_uint(ew1[e]) + 0x8000u) >> 16);
    }
    if (blockIdx.x == 0) {
        int t = threadIdx.x;
        if (t < CS_) {
            float q = 0.f, k = 0.f;
            for (int c = 0; c < CS_; ++c) {
                q += Q1[t * CS_ + c] * Watt1[c];
                k += K1[t * CS_ + c] * Watt1[CS_ + c];
            }
            qv1[t] = q; kv1[t] = k;
        }
        if (t < COUT_) {
            float q = 0.f, k = 0.f;
            for (int c = 0; c < COUT_; ++c) {
                q += Q2[t * COUT_ + c] * Watt2[c];
                k += K2[t * COUT_ + c] * Watt2[COUT_ + c];
            }
            qv2[t] = q; kv2[t] = k;
        }
        if (t == 64) {
            float s1 = 0.f, s2 = 0.f;
            for (int c = 0; c < CS_; ++c) s1 += We1[c] * Watt1[2 * CS_ + c];
            for (int c = 0; c < COUT_; ++c) s2 += We2[c] * Watt2[2 * COUT_ + c];
            se[0] = s1; se[1] = s2;
        }
    }
}

// ---- layer1 node transform: bf16 xs rows + fp32 xd + per-node att scalars ----
__global__ void node_xform1(const float* __restrict__ X, const int* __restrict__ res,
                            const float* __restrict__ Wn,
                            const float* __restrict__ qv, const float* __restrict__ kv,
                            unsigned short* __restrict__ xsb, float* __restrict__ xd_t,
                            float* __restrict__ aj, float* __restrict__ ai) {
    int lane = threadIdx.x & 63;
    int n = blockIdx.x * (blockDim.x >> 6) + (threadIdx.x >> 6);
    if (n >= N1_) return;
    int b = lane >> 4;
    int c = lane & 15;
    int rn = res[n];
    const float4* Xs4 = (const float4*)(X + ((size_t)b * N0_ + n) * CIN_);
    const float4* Xd4 = (const float4*)(X + ((size_t)b * N0_ + rn) * CIN_);
    float s = 0.f, d = 0.f;
#pragma unroll
    for (int k4 = 0; k4 < CIN_ / 4; ++k4) {
        float4 xs4 = Xs4[k4];
        float4 xd4 = Xd4[k4];
        int k = 4 * k4;
        float w0 = Wn[(k + 0) * CS_ + c], w1 = Wn[(k + 1) * CS_ + c];
        float w2 = Wn[(k + 2) * CS_ + c], w3 = Wn[(k + 3) * CS_ + c];
        s += xs4.x * w0 + xs4.y * w1 + xs4.z * w2 + xs4.w * w3;
        d += xd4.x * w0 + xd4.y * w1 + xd4.z * w2 + xd4.w * w3;
    }
    xsb[(size_t)n * 64 + lane] = (unsigned short)((__float_as_uint(s) + 0x8000u) >> 16);
    xd_t[(size_t)n * 64 + lane] = d;
    float p = s * qv[c];
    float q = d * kv[c];
#pragma unroll
    for (int m = 1; m < 16; m <<= 1) {
        p += __shfl_xor(p, m, 16);
        q += __shfl_xor(q, m, 16);
    }
    if (c == 0) {
        aj[n * 4 + b] = p;
        ai[n * 4 + b] = q;
    }
}

// ---- XCD-sliced scatter with fused attention (r14 semantics) ----
template <int SST>
__global__ void scatter_att(const unsigned* __restrict__ pk, const unsigned short* __restrict__ wq,
                            int E, const float* __restrict__ aj, const float* __restrict__ ai,
                            const float* __restrict__ sep, const float* __restrict__ batt,
                            int* __restrict__ cur, uint2* __restrict__ buf) {
    int slice = blockIdx.x & 7;
    int chunk = blockIdx.x >> 3;
    int nch = gridDim.x >> 3;
    float se = sep[0], b0 = batt[0];
    for (int e = chunk * 256 + threadIdx.x; e < E; e += nch * 256) {
        unsigned pv = pk[e];
        int d = pv & 0xffff;
        if (slice_of(d) != slice) continue;
        int s = pv >> 16;
        unsigned wu = (unsigned)wq[e];
        float w = __uint_as_float(wu << 16);
        float4 A = ((const float4*)aj)[s];
        float4 I = ((const float4*)ai)[d];
        float base = fmaf(w, se, b0);
        unsigned q =  __float2uint_rn(sigmoidf_(A.x + I.x + base) * 255.f)
                   | (__float2uint_rn(sigmoidf_(A.y + I.y + base) * 255.f) << 8)
                   | (__float2uint_rn(sigmoidf_(A.z + I.z + base) * 255.f) << 16)
                   | (__float2uint_rn(sigmoidf_(A.w + I.w + base) * 255.f) << 24);
        int p = atomicAdd(&cur[curix(d, SST)], 1);
        if (p < CAP_)
            buf[(size_t)d * CAP_ + p] = make_uint2((wu << 16) | (unsigned)s, q);
    }
}

// ---- layer1 fused edge+epilogue (unroll-8, wave-uniform scalarized slot reads) ----
__global__ void edge_fused1(const int* __restrict__ cur, const uint2* __restrict__ buf,
                            const unsigned short* __restrict__ xsb,
                            const float* __restrict__ xd_t, const float* __restrict__ We,
                            const float* __restrict__ Wc, const float* __restrict__ bc,
                            float* __restrict__ h_t) {
    int lane = threadIdx.x & 63;
    int n = blockIdx.x * (blockDim.x >> 6) + (threadIdx.x >> 6);
    if (n >= N1_) return;
    // n is wave-uniform by construction; tell the compiler so slot/cnt loads scalarize
    n = __builtin_amdgcn_readfirstlane(n);
    int b = lane >> 4;
    int c = lane & 15;
    int sh = 8 * b;
    float wec = We[c];
    float acc = 0.f;
    int cnt = cur[curix(n, SST1_)];
    if (cnt > CAP_) cnt = CAP_;
    const uint2* bp = buf + (size_t)n * CAP_;
    int i = 0;
    for (; i + 8 <= cnt; i += 8) {
        uint2 v[8];
#pragma unroll
        for (int j = 0; j < 8; ++j) v[j] = bp[i + j];
        float xj[8], a[8], g[8];
#pragma unroll
        for (int j = 0; j < 8; ++j) {
            int sj = v[j].x & 0xffff;
            xj[j] = __uint_as_float((unsigned)xsb[(size_t)sj * 64 + lane] << 16);
            a[j] = (float)((v[j].y >> sh) & 0xff) * (1.f / 255.f);
            g[j] = sigmoidf_(__uint_as_float(v[j].x & 0xffff0000u) * wec);
        }
#pragma unroll
        for (int j = 0; j < 8; ++j) acc += a[j] * g[j] * xj[j];
    }
    for (; i < cnt; ++i) {
        uint2 v0 = bp[i];
        int s0 = v0.x & 0xffff;
        float w0 = __uint_as_float(v0.x & 0xffff0000u);
        float xj0 = __uint_as_float((unsigned)xsb[(size_t)s0 * 64 + lane] << 16);
        float a0 = (float)((v0.y >> sh) & 0xff) * (1.f / 255.f);
        acc += a0 * sigmoidf_(w0 * wec) * xj0;
    }
    // fused epilogue
    float xv = xd_t[(size_t)n * 64 + lane];
    float o = bc[c];
#pragma unroll
    for (int k = 0; k < CS_; ++k) {
        o += __shfl(xv, k, 16) * Wc[k * CS_ + c];
        o += __shfl(acc, k, 16) * Wc[(CS_ + k) * CS_ + c];
    }
    float s = o, sq = o * o;
#pragma unroll
    for (int m = 1; m < 64; m <<= 1) {
        s += __shfl_xor(s, m);
        sq += __shfl_xor(sq, m);
    }
    float mean = s * (1.f / 64.f);
    float var = (sq - 64.f * mean * mean) * (1.f / 63.f);
    float inv = __builtin_amdgcn_rsqf(var + EPS_);
    float v = xv + (o - mean) * inv;
    h_t[(size_t)n * 64 + lane] = v > 0.f ? v : 0.01f * v;
}

// ---- layer2 node transform ----
__global__ void node_xform2(const float* __restrict__ h_t, const int* __restrict__ res,
                            const float* __restrict__ Wn,
                            const float* __restrict__ qv, const float* __restrict__ kv,
                            unsigned short* __restrict__ xsb, float* __restrict__ xd_t,
                            float* __restrict__ aj, float* __restrict__ ai) {
    int lane = threadIdx.x & 63;
    int n = blockIdx.x * (blockDim.x >> 6) + (threadIdx.x >> 6);
    if (n >= N2_) return;
    int bl = lane >> 5;
    int c = lane & 31;
    int rn = res[n];
    float qc = qv[c], kc = kv[c];
#pragma unroll
    for (int j = 0; j < 2; ++j) {
        int b = bl + 2 * j;
        const float* hs = h_t + (size_t)n * 64 + b * 16;
        const float* hd = h_t + (size_t)rn * 64 + b * 16;
        float s = 0.f, d = 0.f;
#pragma unroll
        for (int k = 0; k < CS_; ++k) {
            float w = Wn[k * COUT_ + c];
            s += hs[k] * w;
            d += hd[k] * w;
        }
        xsb[(size_t)n * 128 + b * 32 + c] = (unsigned short)((__float_as_uint(s) + 0x8000u) >> 16);
        xd_t[(size_t)n * 128 + b * 32 + c] = d;
        float p = s * qc;
        float q = d * kc;
#pragma unroll
        for (int m = 1; m < 32; m <<= 1) {
            p += __shfl_xor(p, m, 32);
            q += __shfl_xor(q, m, 32);
        }
        if (c == 0) {
            aj[n * 4 + b] = p;
            ai[n * 4 + b] = q;
        }
    }
}

// ---- layer2 fused edge+epilogue -> d_out (unroll-4, scalarized slot reads) ----
__global__ void edge_fused2(const int* __restrict__ cur, const uint2* __restrict__ buf,
                            const unsigned short* __restrict__ xsb,
                            const float* __restrict__ xd_t, const float* __restrict__ We,
                            const float* __restrict__ Wc, const float* __restrict__ bc,
                            float* __restrict__ out) {
    int lane = threadIdx.x & 63;
    int n = blockIdx.x * (blockDim.x >> 6) + (threadIdx.x >> 6);
    if (n >= N2_) return;
    n = __builtin_amdgcn_readfirstlane(n);
    int bl = lane >> 5;
    int c = lane & 31;
    int sh0 = 8 * bl;
    float wec = We[c];
    float acc0 = 0.f, acc1 = 0.f;
    int cnt = cur[curix(n, SST2_)];
    if (cnt > CAP_) cnt = CAP_;
    const uint2* bp = buf + (size_t)n * CAP_;
    int i = 0;
    for (; i + 4 <= cnt; i += 4) {
        uint2 v0 = bp[i], v1 = bp[i + 1], v2 = bp[i + 2], v3 = bp[i + 3];
        int s0 = v0.x & 0xffff, s1 = v1.x & 0xffff;
        int s2 = v2.x & 0xffff, s3 = v3.x & 0xffff;
        float w0 = __uint_as_float(v0.x & 0xffff0000u);
        float w1 = __uint_as_float(v1.x & 0xffff0000u);
        float w2 = __uint_as_float(v2.x & 0xffff0000u);
        float w3 = __uint_as_float(v3.x & 0xffff0000u);
        float xj00 = __uint_as_float((unsigned)xsb[(size_t)s0 * 128 + lane] << 16);
        float xj01 = __uint_as_float((unsigned)xsb[(size_t)s0 * 128 + 64 + lane] << 16);
        float xj10 = __uint_as_float((unsigned)xsb[(size_t)s1 * 128 + lane] << 16);
        float xj11 = __uint_as_float((unsigned)xsb[(size_t)s1 * 128 + 64 + lane] << 16);
        float xj20 = __uint_as_float((unsigned)xsb[(size_t)s2 * 128 + lane] << 16);
        float xj21 = __uint_as_float((unsigned)xsb[(size_t)s2 * 128 + 64 + lane] << 16);
        float xj30 = __uint_as_float((unsigned)xsb[(size_t)s3 * 128 + lane] << 16);
        float xj31 = __uint_as_float((unsigned)xsb[(size_t)s3 * 128 + 64 + lane] << 16);
        float g0 = sigmoidf_(w0 * wec);
        float g1 = sigmoidf_(w1 * wec);
        float g2 = sigmoidf_(w2 * wec);
        float g3 = sigmoidf_(w3 * wec);
        acc0 += (float)((v0.y >> sh0) & 0xff) * (1.f / 255.f) * g0 * xj00;
        acc1 += (float)((v0.y >> (sh0 + 16)) & 0xff) * (1.f / 255.f) * g0 * xj01;
        acc0 += (float)((v1.y >> sh0) & 0xff) * (1.f / 255.f) * g1 * xj10;
        acc1 += (float)((v1.y >> (sh0 + 16)) & 0xff) * (1.f / 255.f) * g1 * xj11;
        acc0 += (float)((v2.y >> sh0) & 0xff) * (1.f / 255.f) * g2 * xj20;
        acc1 += (float)((v2.y >> (sh0 + 16)) & 0xff) * (1.f / 255.f) * g2 * xj21;
        acc0 += (float)((v3.y >> sh0) & 0xff) * (1.f / 255.f) * g3 * xj30;
        acc1 += (float)((v3.y >> (sh0 + 16)) & 0xff) * (1.f / 255.f) * g3 * xj31;
    }
    for (; i < cnt; ++i) {
        uint2 v0 = bp[i];
        int s0 = v0.x & 0xffff;
        float w0 = __uint_as_float(v0.x & 0xffff0000u);
        float xj00 = __uint_as_float((unsigned)xsb[(size_t)s0 * 128 + lane] << 16);
        float xj01 = __uint_as_float((unsigned)xsb[(size_t)s0 * 128 + 64 + lane] << 16);
        float a00 = (float)((v0.y >> sh0) & 0xff) * (1.f / 255.f);
        float a01 = (float)((v0.y >> (sh0 + 16)) & 0xff) * (1.f / 255.f);
        float g0 = sigmoidf_(w0 * wec);
        acc0 += a00 * g0 * xj00;
        acc1 += a01 * g0 * xj01;
    }
    // fused epilogue
    float xv0 = xd_t[(size_t)n * 128 + lane];
    float xv1 = xd_t[(size_t)n * 128 + 64 + lane];
    float o0 = bc[c], o1 = o0;
#pragma unroll
    for (int k = 0; k < COUT_; ++k) {
        float w1 = Wc[k * COUT_ + c];
        float w2 = Wc[(COUT_ + k) * COUT_ + c];
        o0 += __shfl(xv0, k, 32) * w1 + __shfl(acc0, k, 32) * w2;
        o1 += __shfl(xv1, k, 32) * w1 + __shfl(acc1, k, 32) * w2;
    }
    float s = o0 + o1, sq = o0 * o0 + o1 * o1;
#pragma unroll
    for (int m = 1; m < 64; m <<= 1) {
        s += __shfl_xor(s, m);
        sq += __shfl_xor(sq, m);
    }
    float mean = s * (1.f / 128.f);
    float var = (sq - 128.f * mean * mean) * (1.f / 127.f);
    float inv = __builtin_amdgcn_rsqf(var + EPS_);
    float v0 = xv0 + (o0 - mean) * inv;
    float v1 = xv1 + (o1 - mean) * inv;
    out[((size_t)bl * N2_ + n) * COUT_ + c] = v0 > 0.f ? v0 : 0.01f * v0;
    out[((size_t)(bl + 2) * N2_ + n) * COUT_ + c] = v1 > 0.f ? v1 : 0.01f * v1;
}

extern "C" void kernel_launch(void* const* d_in, const int* in_sizes, int n_in,
                              void* d_out, int out_size, void* d_ws, size_t ws_size,
                              hipStream_t stream) {
    (void)in_sizes; (void)n_in; (void)out_size; (void)ws_size;
    const float* X     = (const float*)d_in[0];
    const int*   ei0   = (const int*)d_in[1];
    const float* ew0   = (const float*)d_in[2];
    const int*   rn0   = (const int*)d_in[3];
    const int*   ei1   = (const int*)d_in[4];
    const float* ew1   = (const float*)d_in[5];
    const int*   rn1   = (const int*)d_in[6];
    const float* Wn1   = (const float*)d_in[7];
    const float* We1   = (const float*)d_in[8];
    const float* Q1    = (const float*)d_in[9];
    const float* K1    = (const float*)d_in[10];
    const float* Watt1 = (const float*)d_in[11];
    const float* batt1 = (const float*)d_in[12];
    const float* Wc1   = (const float*)d_in[13];
    const float* bc1   = (const float*)d_in[14];
    const float* Wn2   = (const float*)d_in[15];
    const float* We2   = (const float*)d_in[16];
    const float* Q2    = (const float*)d_in[17];
    const float* K2    = (const float*)d_in[18];
    const float* Watt2 = (const float*)d_in[19];
    const float* batt2 = (const float*)d_in[20];
    const float* Wc2   = (const float*)d_in[21];
    const float* bc2   = (const float*)d_in[22];

    // ---- workspace layout ----
    const size_t BUF = (size_t)B_ * N1_ * CS_;  // 1.6M elements
    float* ws  = (float*)d_ws;
    float* S0  = ws;             // xd1 -> h
    float* S1  = S0 + BUF;       // xd2
    unsigned short* S2 = (unsigned short*)(S1 + BUF);  // xsb (bf16), L1 then L2
    float* aj1 = (float*)(S2 + BUF);
    float* ai1 = aj1 + (size_t)N1_ * 4;
    float* aj2 = ai1 + (size_t)N1_ * 4;
    float* ai2 = aj2 + (size_t)N2_ * 4;
    uint2* ebuf = (uint2*)(ai2 + (size_t)N2_ * 4);   // N1*CAP_ uint2 = 16 MB (L2 reuses)
    int* cur1 = (int*)(ebuf + (size_t)N1_ * CAP_);   // 8*SST1_
    int* cur2 = cur1 + 8 * SST1_;                    // 8*SST2_
    unsigned* pk0 = (unsigned*)(cur2 + 8 * SST2_);   // E0 u32
    unsigned* pk1 = pk0 + E0_;                       // E1 u32
    unsigned short* wq0 = (unsigned short*)(pk1 + E1_);  // E0 u16
    unsigned short* wq1 = wq0 + E0_;                      // E1 u16
    float* qv1 = (float*)(wq1 + E1_);
    float* kv1 = qv1 + 16;
    float* qv2 = kv1 + 16;
    float* kv2 = qv2 + 32;
    float* se  = kv2 + 32;

    const int ztot = 8 * SST1_ + 8 * SST2_;
    pack_prep<<<1024, 256, 0, stream>>>(ei0, ew0, ei1, ew1, pk0, wq0, pk1, wq1,
                                        cur1, ztot,
                                        Q1, K1, Watt1, Q2, K2, Watt2, We1, We2,
                                        qv1, kv1, qv2, kv2, se);

    // ---- layer 1 ----
    node_xform1<<<(N1_ + 3) / 4, 256, 0, stream>>>(X, rn0, Wn1, qv1, kv1, S2, S0, aj1, ai1);
    scatter_att<SST1_><<<4096, 256, 0, stream>>>(pk0, wq0, E0_, aj1, ai1, se, batt1,
                                                 cur1, ebuf);
    edge_fused1<<<(N1_ + 3) / 4, 256, 0, stream>>>(cur1, ebuf, S2, S0, We1, Wc1, bc1, S0);

    // ---- layer 2 (ebuf reused) ----
    node_xform2<<<(N2_ + 3) / 4, 256, 0, stream>>>(S0, rn1, Wn2, qv2, kv2, S2, S1, aj2, ai2);
    scatter_att<SST2_><<<2048, 256, 0, stream>>>(pk1, wq1, E1_, aj2, ai2, se + 1, batt2,
                                                 cur2, ebuf);
    edge_fused2<<<(N2_ + 3) / 4, 256, 0, stream>>>(cur2, ebuf, S2, S1, We2, Wc2, bc2,
                                                   (float*)d_out);
}